// Round 2
// baseline (480.199 us; speedup 1.0000x reference)
//
#include <hip/hip_runtime.h>

#define BATCH 131072
#define SN 32
#define H1 10
#define H2 6
#define TILE_ROWS 64
#define LDS_STRIDE 33   // +1 pad: bank = (row + s) % 32 -> 2-way (free)

__device__ __forceinline__ float fast_tanh(float x) {
    // tanh(x) = 1 - 2/(exp(2x)+1); v_exp_f32 + v_rcp_f32, abs err ~1e-6
    float e = __expf(2.0f * x);
    float r = __builtin_amdgcn_rcpf(e + 1.0f);
    return fmaf(-2.0f, r, 1.0f);
}

// 2048 blocks x 256 threads; each block does 64 rows x all 32 subnets,
// each wave handles 8 subnets (one at a time, lane = row).
__global__ __launch_bounds__(256) void k_main(
    const float* __restrict__ x,
    const float* __restrict__ W1, const float* __restrict__ B1,
    const float* __restrict__ W2, const float* __restrict__ B2,
    const float* __restrict__ W3, const float* __restrict__ B3,
    float* __restrict__ out, double* __restrict__ acc /* [3][SN] */)
{
    __shared__ float xt[TILE_ROWS * LDS_STRIDE];
    const int tid = threadIdx.x;
    const int row0 = blockIdx.x * TILE_ROWS;

    // stage 64x32 x-tile coalesced, transposed-padded into LDS (2 float4/thread)
    const float4* xv = (const float4*)(x + (size_t)row0 * SN);
    #pragma unroll
    for (int it = 0; it < 2; ++it) {
        int v = it * 256 + tid;
        float4 val = xv[v];
        int r = v >> 3;           // 8 float4 per row
        int c = (v & 7) << 2;
        float* dst = &xt[r * LDS_STRIDE + c];
        dst[0] = val.x; dst[1] = val.y; dst[2] = val.z; dst[3] = val.w;
    }
    __syncthreads();

    const int lane = tid & 63;
    const int wave = tid >> 6;    // 0..3

    #pragma unroll 1
    for (int si = 0; si < SN / 4; ++si) {
        // wave-uniform subnet id -> params land in SGPRs via s_load
        const int s = __builtin_amdgcn_readfirstlane(si * 4 + wave);
        const float* w1p = W1 + s * H1;
        const float* b1p = B1 + s * H1;
        const float* w2p = W2 + s * H1 * H2;
        const float* b2p = B2 + s * H2;
        const float* w3p = W3 + s * H2;
        const float b3 = B3[s];

        float w1r[H1], b1r[H1];
        #pragma unroll
        for (int i = 0; i < H1; ++i) { w1r[i] = w1p[i]; b1r[i] = b1p[i]; }
        float w2r[H1 * H2];
        #pragma unroll
        for (int k = 0; k < H1 * H2; ++k) w2r[k] = w2p[k];
        float b2r[H2], w3r[H2];
        #pragma unroll
        for (int j = 0; j < H2; ++j) { b2r[j] = b2p[j]; w3r[j] = w3p[j]; }

        const float xs = xt[lane * LDS_STRIDE + s];

        float t[H1], p[H1], q[H1];
        #pragma unroll
        for (int i = 0; i < H1; ++i) {
            float u = fmaf(xs, w1r[i], b1r[i]);
            float ti = fast_tanh(u);
            float e = fmaf(-ti, ti, 1.0f);              // 1 - t^2
            t[i] = ti;
            p[i] = e * w1r[i];                          // dt/dx
            q[i] = -2.0f * ti * e * w1r[i] * w1r[i];    // d2t/dx2
        }

        float outv = b3, g2 = 0.0f;
        #pragma unroll
        for (int j = 0; j < H2; ++j) {
            float v = b2r[j], a = 0.0f, c = 0.0f;
            #pragma unroll
            for (int i = 0; i < H1; ++i) {
                const float w = w2r[i * H2 + j];
                v = fmaf(w, t[i], v);
                a = fmaf(w, p[i], a);
                c = fmaf(w, q[i], c);
            }
            float sj = fast_tanh(v);
            float dj = fmaf(-sj, sj, 1.0f);             // 1 - s^2
            float g2j = dj * c - 2.0f * sj * dj * a * a;
            outv = fmaf(w3r[j], sj, outv);
            g2   = fmaf(w3r[j], g2j, g2);
        }

        out[(size_t)(row0 + lane) * SN + s] = outv;

        // wave butterfly reduce in f32 (error ~6*2^-24, negligible vs threshold)
        float s1 = outv, s2 = outv * outv, s3 = g2 * g2;
        #pragma unroll
        for (int off = 32; off > 0; off >>= 1) {
            s1 += __shfl_xor(s1, off);
            s2 += __shfl_xor(s2, off);
            s3 += __shfl_xor(s3, off);
        }
        if (lane == 0) {
            atomicAdd(&acc[s],          (double)s1);
            atomicAdd(&acc[SN + s],     (double)s2);
            atomicAdd(&acc[2 * SN + s], (double)s3);
        }
    }
}

// stats recomputed per block from acc (96 doubles, cheap); block 0 writes loss
__global__ __launch_bounds__(256) void k_norm(float* __restrict__ out,
                                              const double* __restrict__ acc)
{
    __shared__ float mean_s[SN], inv_s[SN];
    const int tid = threadIdx.x;
    if (tid < SN) {
        const double invB = 1.0 / (double)BATCH;
        double mean = acc[tid] * invB;
        double var = acc[SN + tid] * invB - mean * mean;
        if (var < 0.0) var = 0.0;
        mean_s[tid] = (float)mean;
        inv_s[tid] = (float)(1.0 / sqrt(var + 1e-10));
    }
    if (blockIdx.x == 0 && tid == 0) {
        const double invB = 1.0 / (double)BATCH;
        double sum = 0.0;
        for (int s = 0; s < SN; ++s) {
            double mean = acc[s] * invB;
            double var = acc[SN + s] * invB - mean * mean;
            if (var < 0.0) var = 0.0;
            sum += (acc[2 * SN + s] * invB) / sqrt(var);   // no eps (matches ref)
        }
        out[(size_t)BATCH * SN] = (float)(0.001 * sum);
    }
    __syncthreads();
    const int v = blockIdx.x * 256 + tid;                  // float4 index
    float4* p = (float4*)out;
    float4 val = p[v];
    const int c = (v & 7) << 2;                            // subnet base
    val.x = (val.x - mean_s[c + 0]) * inv_s[c + 0];
    val.y = (val.y - mean_s[c + 1]) * inv_s[c + 1];
    val.z = (val.z - mean_s[c + 2]) * inv_s[c + 2];
    val.w = (val.w - mean_s[c + 3]) * inv_s[c + 3];
    p[v] = val;
}

extern "C" void kernel_launch(void* const* d_in, const int* in_sizes, int n_in,
                              void* d_out, int out_size, void* d_ws, size_t ws_size,
                              hipStream_t stream) {
    const float* x  = (const float*)d_in[0];
    const float* W1 = (const float*)d_in[1];
    const float* B1 = (const float*)d_in[2];
    const float* W2 = (const float*)d_in[3];
    const float* B2 = (const float*)d_in[4];
    const float* W3 = (const float*)d_in[5];
    const float* B3 = (const float*)d_in[6];

    float* out = (float*)d_out;                       // [BATCH*SN] out_bn, then [1] loss
    double* acc = (double*)d_ws;                      // [3][SN] doubles

    hipMemsetAsync(d_ws, 0, 3 * SN * sizeof(double), stream);

    k_main<<<BATCH / TILE_ROWS, 256, 0, stream>>>(x, W1, B1, W2, B2, W3, B3, out, acc);
    k_norm<<<(BATCH * SN / 4) / 256, 256, 0, stream>>>(out, acc);
}

// Round 3
// 139.506 us; speedup vs baseline: 3.4421x; 3.4421x over previous
//
#include <hip/hip_runtime.h>

#define BATCH 131072
#define SN 32
#define H1 10
#define H2 6
#define TILE_ROWS 64
#define NBLK (BATCH / TILE_ROWS)   // 2048
#define LDS_STRIDE 33              // +1 pad: bank = (row + s) % 32 -> 2-way (free)

__device__ __forceinline__ float fast_tanh(float x) {
    // tanh(x) = 1 - 2/(exp(2x)+1); v_exp_f32 + v_rcp_f32, abs err ~1e-6
    float e = __expf(2.0f * x);
    float r = __builtin_amdgcn_rcpf(e + 1.0f);
    return fmaf(-2.0f, r, 1.0f);
}

// 2048 blocks x 256 threads; each block: 64 rows x all 32 subnets,
// each wave handles 8 subnets (one at a time, lane = row).
// Per-block partial sums -> d_ws (NO atomics; contention was the R2 killer).
__global__ __launch_bounds__(256) void k_main(
    const float* __restrict__ x,
    const float* __restrict__ W1, const float* __restrict__ B1,
    const float* __restrict__ W2, const float* __restrict__ B2,
    const float* __restrict__ W3, const float* __restrict__ B3,
    float* __restrict__ out, float* __restrict__ partial /* [3*SN][NBLK] */)
{
    __shared__ float xt[TILE_ROWS * LDS_STRIDE];
    const int tid = threadIdx.x;
    const int row0 = blockIdx.x * TILE_ROWS;

    // stage 64x32 x-tile coalesced, transposed-padded into LDS (2 float4/thread)
    const float4* xv = (const float4*)(x + (size_t)row0 * SN);
    #pragma unroll
    for (int it = 0; it < 2; ++it) {
        int v = it * 256 + tid;
        float4 val = xv[v];
        int r = v >> 3;           // 8 float4 per row
        int c = (v & 7) << 2;
        float* dst = &xt[r * LDS_STRIDE + c];
        dst[0] = val.x; dst[1] = val.y; dst[2] = val.z; dst[3] = val.w;
    }
    __syncthreads();

    const int lane = tid & 63;
    const int wave = tid >> 6;    // 0..3

    #pragma unroll 1
    for (int si = 0; si < SN / 4; ++si) {
        // wave-uniform subnet id -> params land in SGPRs via s_load
        const int s = __builtin_amdgcn_readfirstlane(si * 4 + wave);
        const float* w1p = W1 + s * H1;
        const float* b1p = B1 + s * H1;
        const float* w2p = W2 + s * H1 * H2;
        const float* b2p = B2 + s * H2;
        const float* w3p = W3 + s * H2;
        const float b3 = B3[s];

        float w1r[H1], b1r[H1];
        #pragma unroll
        for (int i = 0; i < H1; ++i) { w1r[i] = w1p[i]; b1r[i] = b1p[i]; }
        float w2r[H1 * H2];
        #pragma unroll
        for (int k = 0; k < H1 * H2; ++k) w2r[k] = w2p[k];
        float b2r[H2], w3r[H2];
        #pragma unroll
        for (int j = 0; j < H2; ++j) { b2r[j] = b2p[j]; w3r[j] = w3p[j]; }

        const float xs = xt[lane * LDS_STRIDE + s];

        float t[H1], p[H1], q[H1];
        #pragma unroll
        for (int i = 0; i < H1; ++i) {
            float u = fmaf(xs, w1r[i], b1r[i]);
            float ti = fast_tanh(u);
            float e = fmaf(-ti, ti, 1.0f);              // 1 - t^2
            t[i] = ti;
            p[i] = e * w1r[i];                          // dt/dx
            q[i] = -2.0f * ti * e * w1r[i] * w1r[i];    // d2t/dx2
        }

        float outv = b3, g2 = 0.0f;
        #pragma unroll
        for (int j = 0; j < H2; ++j) {
            float v = b2r[j], a = 0.0f, c = 0.0f;
            #pragma unroll
            for (int i = 0; i < H1; ++i) {
                const float w = w2r[i * H2 + j];
                v = fmaf(w, t[i], v);
                a = fmaf(w, p[i], a);
                c = fmaf(w, q[i], c);
            }
            float sj = fast_tanh(v);
            float dj = fmaf(-sj, sj, 1.0f);             // 1 - s^2
            float g2j = dj * c - 2.0f * sj * dj * a * a;
            outv = fmaf(w3r[j], sj, outv);
            g2   = fmaf(w3r[j], g2j, g2);
        }

        out[(size_t)(row0 + lane) * SN + s] = outv;

        // wave butterfly reduce in f32 (64 values/partial; error negligible)
        float s1 = outv, s2 = outv * outv, s3 = g2 * g2;
        #pragma unroll
        for (int off = 32; off > 0; off >>= 1) {
            s1 += __shfl_xor(s1, off);
            s2 += __shfl_xor(s2, off);
            s3 += __shfl_xor(s3, off);
        }
        if (lane == 0) {
            partial[(size_t)(0 * SN + s) * NBLK + blockIdx.x] = s1;
            partial[(size_t)(1 * SN + s) * NBLK + blockIdx.x] = s2;
            partial[(size_t)(2 * SN + s) * NBLK + blockIdx.x] = s3;
        }
    }
}

// 96 blocks: block b sums partial[b][0..NBLK) (coalesced) -> acc[b] (double)
__global__ __launch_bounds__(256) void k_reduce(const float* __restrict__ partial,
                                                double* __restrict__ acc)
{
    const float* p = partial + (size_t)blockIdx.x * NBLK;
    double s = 0.0;
    for (int i = threadIdx.x; i < NBLK; i += 256) s += (double)p[i];
    #pragma unroll
    for (int off = 32; off > 0; off >>= 1) s += __shfl_down(s, off);
    __shared__ double ws[4];
    if ((threadIdx.x & 63) == 0) ws[threadIdx.x >> 6] = s;
    __syncthreads();
    if (threadIdx.x == 0) acc[blockIdx.x] = ws[0] + ws[1] + ws[2] + ws[3];
}

// stats recomputed per block from acc (96 doubles, cheap); block 0 writes loss
__global__ __launch_bounds__(256) void k_norm(float* __restrict__ out,
                                              const double* __restrict__ acc)
{
    __shared__ float mean_s[SN], inv_s[SN];
    const int tid = threadIdx.x;
    if (tid < SN) {
        const double invB = 1.0 / (double)BATCH;
        double mean = acc[tid] * invB;
        double var = acc[SN + tid] * invB - mean * mean;
        if (var < 0.0) var = 0.0;
        mean_s[tid] = (float)mean;
        inv_s[tid] = (float)(1.0 / sqrt(var + 1e-10));
    }
    if (blockIdx.x == 0 && tid == 0) {
        const double invB = 1.0 / (double)BATCH;
        double sum = 0.0;
        for (int s = 0; s < SN; ++s) {
            double mean = acc[s] * invB;
            double var = acc[SN + s] * invB - mean * mean;
            if (var < 0.0) var = 0.0;
            sum += (acc[2 * SN + s] * invB) / sqrt(var);   // no eps (matches ref)
        }
        out[(size_t)BATCH * SN] = (float)(0.001 * sum);
    }
    __syncthreads();
    const int v = blockIdx.x * 256 + tid;                  // float4 index
    float4* p = (float4*)out;
    float4 val = p[v];
    const int c = (v & 7) << 2;                            // subnet base
    val.x = (val.x - mean_s[c + 0]) * inv_s[c + 0];
    val.y = (val.y - mean_s[c + 1]) * inv_s[c + 1];
    val.z = (val.z - mean_s[c + 2]) * inv_s[c + 2];
    val.w = (val.w - mean_s[c + 3]) * inv_s[c + 3];
    p[v] = val;
}

extern "C" void kernel_launch(void* const* d_in, const int* in_sizes, int n_in,
                              void* d_out, int out_size, void* d_ws, size_t ws_size,
                              hipStream_t stream) {
    const float* x  = (const float*)d_in[0];
    const float* W1 = (const float*)d_in[1];
    const float* B1 = (const float*)d_in[2];
    const float* W2 = (const float*)d_in[3];
    const float* B2 = (const float*)d_in[4];
    const float* W3 = (const float*)d_in[5];
    const float* B3 = (const float*)d_in[6];

    float* out = (float*)d_out;                 // [BATCH*SN] out_bn, then [1] loss
    float* partial = (float*)d_ws;              // [3*SN][NBLK] f32, fully overwritten
    double* acc = (double*)((char*)d_ws + (size_t)3 * SN * NBLK * sizeof(float));

    k_main<<<NBLK, 256, 0, stream>>>(x, W1, B1, W2, B2, W3, B3, out, partial);
    k_reduce<<<3 * SN, 256, 0, stream>>>(partial, acc);
    k_norm<<<(BATCH * SN / 4) / 256, 256, 0, stream>>>(out, acc);
}

// Round 6
// 123.811 us; speedup vs baseline: 3.8785x; 1.1268x over previous
//
#include <hip/hip_runtime.h>

#define BATCH 131072
#define SN 32
#define H1 10
#define H2 6
#define ROWS 128                           // rows per block; lane pairs (lane, lane+64)
#define GRID (BATCH / ROWS)                // 1024
#define LDS_STRIDE 33                      // bank = (row + s) % 32 -> 2-way (free)

typedef float v2f __attribute__((ext_vector_type(2)));

__device__ __forceinline__ v2f bc(float s) { v2f r; r.x = s; r.y = s; return r; }
__device__ __forceinline__ v2f fma2(v2f a, v2f b, v2f c) {
    return __builtin_elementwise_fma(a, b, c);   // -> v_pk_fma_f32
}
__device__ __forceinline__ v2f tanh2(v2f x) {
    // tanh(x) = 1 - 2/(exp(2x)+1); exp/rcp scalar per component, rest packed
    v2f x2 = x + x;
    v2f e; e.x = __expf(x2.x); e.y = __expf(x2.y);
    v2f e1 = e + bc(1.0f);
    v2f r; r.x = __builtin_amdgcn_rcpf(e1.x); r.y = __builtin_amdgcn_rcpf(e1.y);
    return fma2(bc(-2.0f), r, bc(1.0f));
}

// 1024 blocks x 256 threads; block: 128 rows x 32 subnets; wave handles 8
// subnets sequentially, each lane computes a ROW PAIR via packed fp32.
__global__ __launch_bounds__(256) void k_main(
    const float* __restrict__ x,
    const float* __restrict__ W1, const float* __restrict__ B1,
    const float* __restrict__ W2, const float* __restrict__ B2,
    const float* __restrict__ W3, const float* __restrict__ B3,
    float* __restrict__ out, float* __restrict__ partial /* [3*SN][GRID] */)
{
    __shared__ float xt[ROWS * LDS_STRIDE];   // 16.9 KB
    __shared__ float ov[ROWS * LDS_STRIDE];   // raw outputs staged for coalesced store
    const int tid = threadIdx.x;
    const int lane = tid & 63;
    const int wave = tid >> 6;                // 0..3
    const int blk = blockIdx.x;

    // stage 128x32 x-tile coalesced, transpose-pad into LDS (4 float4/thread)
    const float4* xv = (const float4*)(x + (size_t)blk * ROWS * SN);
    #pragma unroll
    for (int it = 0; it < 4; ++it) {
        int v = it * 256 + tid;
        float4 val = xv[v];
        int r = v >> 3;                       // 8 float4 per row
        int c = (v & 7) << 2;
        float* dst = &xt[r * LDS_STRIDE + c];
        dst[0] = val.x; dst[1] = val.y; dst[2] = val.z; dst[3] = val.w;
    }
    __syncthreads();

    #pragma unroll 1
    for (int si = 0; si < 8; ++si) {
        // wave-uniform subnet id -> params land in SGPRs via s_load
        const int s = __builtin_amdgcn_readfirstlane(si * 4 + wave);
        const float* w1p = W1 + s * H1;
        const float* b1p = B1 + s * H1;
        const float* w2p = W2 + s * H1 * H2;
        const float* b2p = B2 + s * H2;
        const float* w3p = W3 + s * H2;
        const float b3 = B3[s];

        float w1r[H1], b1r[H1];
        #pragma unroll
        for (int i = 0; i < H1; ++i) { w1r[i] = w1p[i]; b1r[i] = b1p[i]; }
        float w2r[H1 * H2];
        #pragma unroll
        for (int k = 0; k < H1 * H2; ++k) w2r[k] = w2p[k];
        float b2r[H2], w3r[H2];
        #pragma unroll
        for (int j = 0; j < H2; ++j) { b2r[j] = b2p[j]; w3r[j] = w3p[j]; }

        v2f xs;
        xs.x = xt[lane * LDS_STRIDE + s];
        xs.y = xt[(lane + 64) * LDS_STRIDE + s];

        // layer 1: t = tanh(x w1 + b1); p = (1-t^2) w1; q' = t (1-t^2) w1^2
        // (true d2 = -2 q'; the -2 is reassociated into the g2 epilogue)
        v2f t[H1], p[H1], q[H1];
        #pragma unroll
        for (int i = 0; i < H1; ++i) {
            v2f u = fma2(xs, bc(w1r[i]), bc(b1r[i]));
            v2f ti = tanh2(u);
            v2f e = fma2(-ti, ti, bc(1.0f));
            t[i] = ti;
            p[i] = e * bc(w1r[i]);
            q[i] = (ti * p[i]) * bc(w1r[i]);
        }

        v2f o = bc(b3), g2a = bc(0.0f);
        #pragma unroll
        for (int j = 0; j < H2; ++j) {
            v2f vv = bc(b2r[j]), a = bc(0.0f), c = bc(0.0f);
            #pragma unroll
            for (int i = 0; i < H1; ++i) {
                v2f wb = bc(w2r[i * H2 + j]);
                vv = fma2(wb, t[i], vv);
                a  = fma2(wb, p[i], a);
                c  = fma2(wb, q[i], c);
            }
            v2f sj = tanh2(vv);
            v2f dj = fma2(-sj, sj, bc(1.0f));            // 1 - s^2
            v2f aa = a * a;
            v2f h  = fma2(sj, aa, c);                    // c' + s a^2
            v2f k  = dj * h;                             // g2_j = -2 k
            o   = fma2(bc(w3r[j]), sj, o);
            g2a = fma2(bc(w3r[j]), k, g2a);              // g2_true = -2 g2a
        }

        // stage raw outputs in LDS (bank = (lane+s)%32, 2-way free)
        ov[lane * LDS_STRIDE + s] = o.x;
        ov[(lane + 64) * LDS_STRIDE + s] = o.y;

        // per-pair partial sums, horizontal add, wave butterfly reduce
        v2f s2v = o * o;
        v2f s3v = (g2a * g2a) * bc(4.0f);                // (-2 g2a)^2
        float s1 = o.x + o.y;
        float s2 = s2v.x + s2v.y;
        float s3 = s3v.x + s3v.y;
        #pragma unroll
        for (int off = 32; off > 0; off >>= 1) {
            s1 += __shfl_xor(s1, off);
            s2 += __shfl_xor(s2, off);
            s3 += __shfl_xor(s3, off);
        }
        if (lane == 0) {
            partial[(size_t)(0 * SN + s) * GRID + blk] = s1;
            partial[(size_t)(1 * SN + s) * GRID + blk] = s2;
            partial[(size_t)(2 * SN + s) * GRID + blk] = s3;
        }
    }
    __syncthreads();

    // coalesced raw-output store: lane reads 4 floats (banks 4k+r, conflict-free)
    float4* po = (float4*)out;
    const size_t base = (size_t)blk * (ROWS * SN / 4);
    #pragma unroll
    for (int it = 0; it < 4; ++it) {
        int v = it * 256 + tid;
        int r = v >> 3;
        int c = (v & 7) << 2;
        const float* src = &ov[r * LDS_STRIDE + c];
        float4 w; w.x = src[0]; w.y = src[1]; w.z = src[2]; w.w = src[3];
        po[base + v] = w;
    }
}

// 96 blocks: block b sums partial[b][0..GRID) (coalesced) -> acc[b] (double)
__global__ __launch_bounds__(256) void k_reduce(const float* __restrict__ partial,
                                                double* __restrict__ acc)
{
    const float* p = partial + (size_t)blockIdx.x * GRID;
    double s = 0.0;
    for (int i = threadIdx.x; i < GRID; i += 256) s += (double)p[i];
    #pragma unroll
    for (int off = 32; off > 0; off >>= 1) s += __shfl_down(s, off);
    __shared__ double ws[4];
    if ((threadIdx.x & 63) == 0) ws[threadIdx.x >> 6] = s;
    __syncthreads();
    if (threadIdx.x == 0) acc[blockIdx.x] = ws[0] + ws[1] + ws[2] + ws[3];
}

// stats recomputed per block from acc (96 doubles, cheap); block 0 writes loss
__global__ __launch_bounds__(256) void k_norm(float* __restrict__ out,
                                              const double* __restrict__ acc)
{
    __shared__ float mean_s[SN], inv_s[SN];
    const int tid = threadIdx.x;
    if (tid < SN) {
        const double invB = 1.0 / (double)BATCH;
        double mean = acc[tid] * invB;
        double var = acc[SN + tid] * invB - mean * mean;
        if (var < 0.0) var = 0.0;
        mean_s[tid] = (float)mean;
        inv_s[tid] = (float)(1.0 / sqrt(var + 1e-10));
    }
    if (blockIdx.x == 0 && tid == 0) {
        const double invB = 1.0 / (double)BATCH;
        double sum = 0.0;
        for (int s = 0; s < SN; ++s) {
            double mean = acc[s] * invB;
            double var = acc[SN + s] * invB - mean * mean;
            if (var < 0.0) var = 0.0;
            sum += (acc[2 * SN + s] * invB) / sqrt(var);   // no eps (matches ref)
        }
        out[(size_t)BATCH * SN] = (float)(0.001 * sum);
    }
    __syncthreads();
    const int v = blockIdx.x * 256 + tid;                  // float4 index
    float4* p = (float4*)out;
    float4 val = p[v];
    const int c = (v & 7) << 2;                            // subnet base
    val.x = (val.x - mean_s[c + 0]) * inv_s[c + 0];
    val.y = (val.y - mean_s[c + 1]) * inv_s[c + 1];
    val.z = (val.z - mean_s[c + 2]) * inv_s[c + 2];
    val.w = (val.w - mean_s[c + 3]) * inv_s[c + 3];
    p[v] = val;
}

extern "C" void kernel_launch(void* const* d_in, const int* in_sizes, int n_in,
                              void* d_out, int out_size, void* d_ws, size_t ws_size,
                              hipStream_t stream) {
    const float* x  = (const float*)d_in[0];
    const float* W1 = (const float*)d_in[1];
    const float* B1 = (const float*)d_in[2];
    const float* W2 = (const float*)d_in[3];
    const float* B2 = (const float*)d_in[4];
    const float* W3 = (const float*)d_in[5];
    const float* B3 = (const float*)d_in[6];

    float* out = (float*)d_out;                 // [BATCH*SN] out_bn, then [1] loss
    float* partial = (float*)d_ws;              // [3*SN][GRID] f32, fully overwritten
    double* acc = (double*)((char*)d_ws + (size_t)3 * SN * GRID * sizeof(float));

    k_main<<<GRID, 256, 0, stream>>>(x, W1, B1, W2, B2, W3, B3, out, partial);
    k_reduce<<<3 * SN, 256, 0, stream>>>(partial, acc);
    k_norm<<<(BATCH * SN / 4) / 256, 256, 0, stream>>>(out, acc);
}